// Round 1
// baseline (333.508 us; speedup 1.0000x reference)
//
#include <hip/hip_runtime.h>

#define H 1024
#define W 1024
#define K 11
#define RAD 5
#define TX 32
#define TY 32
#define EX (TX + K - 1)   /* 42 */
#define EY (TY + K - 1)   /* 42 */
#define SRS (EX + 1)      /* raw tile stride 43 (odd -> conflict-free) */
#define PLS (TX + 1)      /* plane stride 33 (odd -> conflict-free) */

__global__ void zero_out_kernel(float* out) {
    if (threadIdx.x == 0) out[0] = 0.0f;
}

__launch_bounds__(256)
__global__ void ssim_kernel(const float* __restrict__ img1,
                            const float* __restrict__ img2,
                            const float* __restrict__ kern,
                            float* __restrict__ out,
                            float inv_n) {
    __shared__ float g[K];
    __shared__ float sx[EY * SRS];
    __shared__ float sy[EY * SRS];
    __shared__ float hmx[EY * PLS];
    __shared__ float hmy[EY * PLS];
    __shared__ float hxx[EY * PLS];
    __shared__ float hyy[EY * PLS];
    __shared__ float hxy[EY * PLS];
    __shared__ float wsum[4];

    const int tid = threadIdx.x;
    const int bx = blockIdx.x;
    const int by = blockIdx.y;
    const int b  = blockIdx.z;

    // 1D gaussian factor = row sums of the normalized 2D kernel (exact).
    if (tid < K) {
        float s = 0.0f;
        #pragma unroll
        for (int j = 0; j < K; ++j) s += kern[tid * K + j];
        g[tid] = s;
    }

    const float* __restrict__ p1 = img1 + (size_t)b * H * W;
    const float* __restrict__ p2 = img2 + (size_t)b * H * W;
    const int row0 = by * TY - RAD;
    const int col0 = bx * TX - RAD;

    // Stage raw tiles (with SAME zero padding) into LDS.
    for (int i = tid; i < EY * EX; i += 256) {
        int r = i / EX;
        int c = i - r * EX;
        int gr = row0 + r;
        int gc = col0 + c;
        float vx = 0.0f, vy = 0.0f;
        if ((unsigned)gr < (unsigned)H && (unsigned)gc < (unsigned)W) {
            size_t idx = (size_t)gr * W + gc;
            vx = p1[idx];
            vy = p2[idx];
        }
        sx[r * SRS + c] = vx;
        sy[r * SRS + c] = vy;
    }
    __syncthreads();

    // Horizontal pass over EY rows x TX cols: 5 separable partial sums.
    for (int i = tid; i < EY * TX; i += 256) {
        int r = i >> 5;          // TX == 32
        int c = i & (TX - 1);
        float smx = 0.f, smy = 0.f, sxx = 0.f, syy = 0.f, sxy = 0.f;
        const float* rx = &sx[r * SRS + c];
        const float* ry = &sy[r * SRS + c];
        #pragma unroll
        for (int j = 0; j < K; ++j) {
            float w = g[j];
            float x = rx[j];
            float y = ry[j];
            float wx = w * x;
            float wy = w * y;
            smx += wx;
            smy += wy;
            sxx = fmaf(wx, x, sxx);
            syy = fmaf(wy, y, syy);
            sxy = fmaf(wx, y, sxy);
        }
        int o = r * PLS + c;
        hmx[o] = smx; hmy[o] = smy; hxx[o] = sxx; hyy[o] = syy; hxy[o] = sxy;
    }
    __syncthreads();

    // Vertical pass + SSIM map + per-thread accumulation.
    const float C1 = 1e-4f;      // 0.01^2
    const float C2 = 9e-4f;      // 0.03^2
    float acc = 0.0f;
    for (int i = tid; i < TY * TX; i += 256) {
        int r = i >> 5;
        int c = i & (TX - 1);
        float mx = 0.f, my = 0.f, xx = 0.f, yy = 0.f, xy = 0.f;
        #pragma unroll
        for (int j = 0; j < K; ++j) {
            float w = g[j];
            int o = (r + j) * PLS + c;
            mx = fmaf(w, hmx[o], mx);
            my = fmaf(w, hmy[o], my);
            xx = fmaf(w, hxx[o], xx);
            yy = fmaf(w, hyy[o], yy);
            xy = fmaf(w, hxy[o], xy);
        }
        float mx2 = mx * mx;
        float my2 = my * my;
        float mxy = mx * my;
        float sx2 = xx - mx2;
        float sy2 = yy - my2;
        float sxyv = xy - mxy;
        float num = (2.0f * mxy + C1) * (2.0f * sxyv + C2);
        float den = (mx2 + my2 + C1) * (sx2 + sy2 + C2);
        acc += num / den;
    }

    // Wave (64-lane) butterfly reduce, then cross-wave via LDS, one atomic.
    for (int off = 32; off > 0; off >>= 1)
        acc += __shfl_down(acc, off, 64);
    if ((tid & 63) == 0) wsum[tid >> 6] = acc;
    __syncthreads();
    if (tid == 0) {
        float s = wsum[0] + wsum[1] + wsum[2] + wsum[3];
        atomicAdd(out, s * inv_n);
    }
}

extern "C" void kernel_launch(void* const* d_in, const int* in_sizes, int n_in,
                              void* d_out, int out_size, void* d_ws, size_t ws_size,
                              hipStream_t stream) {
    const float* img1 = (const float*)d_in[0];
    const float* img2 = (const float*)d_in[1];
    const float* kern = (const float*)d_in[2];
    float* out = (float*)d_out;

    const int B = in_sizes[0] / (H * W);
    const float inv_n = 1.0f / ((float)B * (float)H * (float)W);

    zero_out_kernel<<<dim3(1), dim3(64), 0, stream>>>(out);

    dim3 grid(W / TX, H / TY, B);
    ssim_kernel<<<grid, dim3(256), 0, stream>>>(img1, img2, kern, out, inv_n);
}

// Round 2
// 300.149 us; speedup vs baseline: 1.1111x; 1.1111x over previous
//
#include <hip/hip_runtime.h>

#define H 1024
#define W 1024
#define K 11
#define RAD 5
#define TX 32            /* tile width  (outputs) */
#define TY 64            /* tile height (outputs) */
#define EX (TX + K - 1)  /* 42 raw cols needed */
#define EY (TY + K - 1)  /* 74 raw rows needed */
#define SRS 44           /* raw tile stride: mult of 4 (16B align), 44%32=12 -> 2-way only */
#define PLS 36           /* plane stride:    mult of 4, 36%32=4  -> 2-way only */

__global__ void zero_out_kernel(float* out) {
    if (threadIdx.x == 0) out[0] = 0.0f;
}

__launch_bounds__(256, 2)
__global__ void ssim_kernel(const float* __restrict__ img1,
                            const float* __restrict__ img2,
                            const float* __restrict__ kern,
                            float* __restrict__ out,
                            float inv_n) {
    __shared__ float g[K];
    __shared__ __align__(16) float sx[EY * SRS];
    __shared__ __align__(16) float sy[EY * SRS];
    __shared__ __align__(16) float hmx[EY * PLS];
    __shared__ __align__(16) float hmy[EY * PLS];
    __shared__ __align__(16) float hxx[EY * PLS];
    __shared__ __align__(16) float hyy[EY * PLS];
    __shared__ __align__(16) float hxy[EY * PLS];
    __shared__ float wsum[4];

    const int tid = threadIdx.x;
    const int bx = blockIdx.x;
    const int by = blockIdx.y;
    const int b  = blockIdx.z;

    // 1D gaussian factor = row sums of the normalized 2D kernel (exact).
    if (tid < K) {
        float s = 0.0f;
        #pragma unroll
        for (int j = 0; j < K; ++j) s += kern[tid * K + j];
        g[tid] = s;
    }

    const float* __restrict__ p1 = img1 + (size_t)b * H * W;
    const float* __restrict__ p2 = img2 + (size_t)b * H * W;
    const int row0 = by * TY - RAD;
    const int col0 = bx * TX - RAD;

    // ---- Stage raw tiles into LDS (fast path for interior blocks) ----
    const bool interior = (row0 >= 0) & (row0 + EY <= H) & (col0 >= 0) & (col0 + EX <= W);
    if (interior) {
        for (int i = tid; i < EY * EX; i += 256) {
            int r = i / EX;
            int c = i - r * EX;
            size_t idx = (size_t)(row0 + r) * W + (col0 + c);
            sx[r * SRS + c] = p1[idx];
            sy[r * SRS + c] = p2[idx];
        }
    } else {
        for (int i = tid; i < EY * EX; i += 256) {
            int r = i / EX;
            int c = i - r * EX;
            int gr = row0 + r;
            int gc = col0 + c;
            float vx = 0.0f, vy = 0.0f;
            if ((unsigned)gr < (unsigned)H && (unsigned)gc < (unsigned)W) {
                size_t idx = (size_t)gr * W + gc;
                vx = p1[idx];
                vy = p2[idx];
            }
            sx[r * SRS + c] = vx;
            sy[r * SRS + c] = vy;
        }
    }
    __syncthreads();

    // Gaussian weights into registers (no per-tap LDS broadcast reads).
    float gw[K];
    #pragma unroll
    for (int j = 0; j < K; ++j) gw[j] = g[j];

    // ---- Horizontal pass: 4 columns per thread, b128 LDS reads/writes ----
    // EY rows x (TX/4)=8 col-groups = 592 work items.
    for (int i = tid; i < EY * 8; i += 256) {
        int r  = i >> 3;
        int cg = (i & 7) << 2;
        const float* rx = &sx[r * SRS + cg];
        const float* ry = &sy[r * SRS + cg];
        float x[16], y[16];
        #pragma unroll
        for (int q = 0; q < 4; ++q) {
            float4 vx = *(const float4*)&rx[4 * q];
            float4 vy = *(const float4*)&ry[4 * q];
            x[4*q+0] = vx.x; x[4*q+1] = vx.y; x[4*q+2] = vx.z; x[4*q+3] = vx.w;
            y[4*q+0] = vy.x; y[4*q+1] = vy.y; y[4*q+2] = vy.z; y[4*q+3] = vy.w;
        }
        float smx[4] = {0,0,0,0}, smy[4] = {0,0,0,0};
        float sxx[4] = {0,0,0,0}, syy[4] = {0,0,0,0}, sxy[4] = {0,0,0,0};
        #pragma unroll
        for (int j = 0; j < K; ++j) {
            float w = gw[j];
            #pragma unroll
            for (int k = 0; k < 4; ++k) {
                float xv = x[k + j];
                float yv = y[k + j];
                float wx = w * xv;
                float wy = w * yv;
                smx[k] += wx;
                smy[k] += wy;
                sxx[k] = fmaf(wx, xv, sxx[k]);
                syy[k] = fmaf(wy, yv, syy[k]);
                sxy[k] = fmaf(wx, yv, sxy[k]);
            }
        }
        int o = r * PLS + cg;
        *(float4*)&hmx[o] = make_float4(smx[0], smx[1], smx[2], smx[3]);
        *(float4*)&hmy[o] = make_float4(smy[0], smy[1], smy[2], smy[3]);
        *(float4*)&hxx[o] = make_float4(sxx[0], sxx[1], sxx[2], sxx[3]);
        *(float4*)&hyy[o] = make_float4(syy[0], syy[1], syy[2], syy[3]);
        *(float4*)&hxy[o] = make_float4(sxy[0], sxy[1], sxy[2], sxy[3]);
    }
    __syncthreads();

    // ---- Vertical pass: 1 col x 8 rows per thread, each plane value read once ----
    const int col = tid & 31;
    const int r0  = (tid >> 5) << 3;   // 0,8,...,56
    float amx[8], amy[8], axx[8], ayy[8], axy[8];
    #pragma unroll
    for (int k = 0; k < 8; ++k) { amx[k]=0.f; amy[k]=0.f; axx[k]=0.f; ayy[k]=0.f; axy[k]=0.f; }

    #pragma unroll
    for (int j = 0; j < 18; ++j) {      // 8 rows + 10 halo
        int o = (r0 + j) * PLS + col;
        float vmx = hmx[o];
        float vmy = hmy[o];
        float vxx = hxx[o];
        float vyy = hyy[o];
        float vxy = hxy[o];
        #pragma unroll
        for (int k = 0; k < 8; ++k) {
            if (j - k >= 0 && j - k <= 10) {   // static after full unroll
                float w = gw[j - k];
                amx[k] = fmaf(w, vmx, amx[k]);
                amy[k] = fmaf(w, vmy, amy[k]);
                axx[k] = fmaf(w, vxx, axx[k]);
                ayy[k] = fmaf(w, vyy, ayy[k]);
                axy[k] = fmaf(w, vxy, axy[k]);
            }
        }
    }

    // ---- SSIM map + per-thread accumulation ----
    const float C1 = 1e-4f;
    const float C2 = 9e-4f;
    float acc = 0.0f;
    #pragma unroll
    for (int k = 0; k < 8; ++k) {
        float mx = amx[k], my = amy[k];
        float mx2 = mx * mx;
        float my2 = my * my;
        float mxy = mx * my;
        float sx2  = axx[k] - mx2;
        float sy2  = ayy[k] - my2;
        float sxyv = axy[k] - mxy;
        float num = (2.0f * mxy + C1) * (2.0f * sxyv + C2);
        float den = (mx2 + my2 + C1) * (sx2 + sy2 + C2);
        acc += num * __builtin_amdgcn_rcpf(den);
    }

    // ---- Wave butterfly reduce -> cross-wave via LDS -> one atomic ----
    for (int off = 32; off > 0; off >>= 1)
        acc += __shfl_down(acc, off, 64);
    if ((tid & 63) == 0) wsum[tid >> 6] = acc;
    __syncthreads();
    if (tid == 0) {
        float s = wsum[0] + wsum[1] + wsum[2] + wsum[3];
        atomicAdd(out, s * inv_n);
    }
}

extern "C" void kernel_launch(void* const* d_in, const int* in_sizes, int n_in,
                              void* d_out, int out_size, void* d_ws, size_t ws_size,
                              hipStream_t stream) {
    const float* img1 = (const float*)d_in[0];
    const float* img2 = (const float*)d_in[1];
    const float* kern = (const float*)d_in[2];
    float* out = (float*)d_out;

    const int B = in_sizes[0] / (H * W);
    const float inv_n = 1.0f / ((float)B * (float)H * (float)W);

    zero_out_kernel<<<dim3(1), dim3(64), 0, stream>>>(out);

    dim3 grid(W / TX, H / TY, B);
    ssim_kernel<<<grid, dim3(256), 0, stream>>>(img1, img2, kern, out, inv_n);
}